// Round 1
// baseline (49.077 us; speedup 1.0000x reference)
//
#include <hip/hip_runtime.h>
#include <math.h>

// Problem constants (from reference setup_inputs)
#define B_TOT 32
#define C_TOT 128
#define G_TOT 4096
#define BODY  4
#define M_TOT 5

// Tiling
#define B_PER 4            // batch rows staged in LDS per block (4*16KB = 64KB)
#define CQ    8            // c-loop split across 8 adjacent lanes
#define GPB   64           // g outputs per block
#define THREADS (GPB*CQ)   // 512
#define C_PER (C_TOT/CQ)   // 16 c-iterations per thread

// ---- tiny softmax over W (5 x 128), one wave ----
__global__ void softmax_w_kernel(const float* __restrict__ W, float* __restrict__ Wm) {
    const int lane = threadIdx.x; // 64 threads
    for (int m = 0; m < M_TOT; ++m) {
        float a = W[m * C_TOT + lane];
        float b = W[m * C_TOT + lane + 64];
        float mx = fmaxf(a, b);
        #pragma unroll
        for (int off = 32; off; off >>= 1) mx = fmaxf(mx, __shfl_xor(mx, off));
        float ea = expf(a - mx), eb = expf(b - mx);
        float s = ea + eb;
        #pragma unroll
        for (int off = 32; off; off >>= 1) s += __shfl_xor(s, off);
        Wm[m * C_TOT + lane]      = ea / s;
        Wm[m * C_TOT + lane + 64] = eb / s;
    }
}

// ---- one t-step: v_out = softor(v_in, softor_m(h)) ----
__global__ __launch_bounds__(THREADS, 4) void step_kernel(
    const float* __restrict__ v_in,   // (B, G)
    const int*   __restrict__ X,      // (C, G, 4) int32
    const int*   __restrict__ fact,   // (C, G) int32 (0/1)
    const float* __restrict__ Wm,     // (5, 128) softmaxed
    float*       __restrict__ v_out)  // (B, G)
{
    __shared__ float lv[B_PER][G_TOT];     // 64 KB: full v rows for this b-group
    __shared__ float lw[M_TOT][C_TOT];     // 2.5 KB

    const int tid = threadIdx.x;
    const int b0  = blockIdx.y * B_PER;
    const int gt  = blockIdx.x * GPB;

    // stage Wm
    for (int i = tid; i < M_TOT * C_TOT; i += THREADS)
        ((float*)lw)[i] = Wm[i];
    // stage v rows (float4-vectorized, coalesced)
    {
        const float4* vsrc = (const float4*)(v_in + (size_t)b0 * G_TOT);
        float4* vdst = (float4*)&lv[0][0];
        #pragma unroll
        for (int i = tid; i < B_PER * G_TOT / 4; i += THREADS)
            vdst[i] = vsrc[i];
    }
    __syncthreads();

    const int cq = tid & (CQ - 1);
    const int gl = tid >> 3;          // log2(CQ) = 3
    const int g  = gt + gl;

    float h[M_TOT][B_PER];
    #pragma unroll
    for (int m = 0; m < M_TOT; ++m)
        #pragma unroll
        for (int b = 0; b < B_PER; ++b) h[m][b] = 0.0f;

    const int cbase = cq * C_PER;
    #pragma unroll 4
    for (int ci = 0; ci < C_PER; ++ci) {
        const int c = cbase + ci;
        // X[c][g][0..3] as one int4 (coalesced per cq-group)
        const int4 xi = ((const int4*)X)[(size_t)c * G_TOT + g];
        const int  fm = fact[(size_t)c * G_TOT + g];
        const float w0 = lw[0][c], w1 = lw[1][c], w2 = lw[2][c],
                    w3 = lw[3][c], w4 = lw[4][c];
        #pragma unroll
        for (int b = 0; b < B_PER; ++b) {
            float p = lv[b][xi.x] * lv[b][xi.y] * lv[b][xi.z] * lv[b][xi.w];
            p = fm ? 1.0f : p;
            h[0][b] += w0 * p;
            h[1][b] += w1 * p;
            h[2][b] += w2 * p;
            h[3][b] += w3 * p;
            h[4][b] += w4 * p;
        }
    }

    // reduce partial h over the 8 cq lanes (adjacent lanes, same wave)
    #pragma unroll
    for (int m = 0; m < M_TOT; ++m)
        #pragma unroll
        for (int b = 0; b < B_PER; ++b) {
            float s = h[m][b];
            s += __shfl_xor(s, 1);
            s += __shfl_xor(s, 2);
            s += __shfl_xor(s, 4);
            h[m][b] = s;
        }

    if (cq == 0) {
        #pragma unroll
        for (int b = 0; b < B_PER; ++b) {
            float om = 1.0f;
            #pragma unroll
            for (int m = 0; m < M_TOT; ++m) om *= (1.0f - h[m][b]);
            float r = 1.0f - om;
            r = fminf(fmaxf(r, 0.0f), 1.0f);
            const float vold = lv[b][g];
            float vn = 1.0f - (1.0f - vold) * (1.0f - r);
            vn = fminf(fmaxf(vn, 0.0f), 1.0f);
            v_out[(size_t)(b0 + b) * G_TOT + g] = vn;
        }
    }
}

extern "C" void kernel_launch(void* const* d_in, const int* in_sizes, int n_in,
                              void* d_out, int out_size, void* d_ws, size_t ws_size,
                              hipStream_t stream) {
    const float* v0   = (const float*)d_in[0];
    const int*   X    = (const int*)  d_in[1];   // int64 in ref -> int32 on device
    const int*   fact = (const int*)  d_in[2];   // bool in ref  -> int32 on device
    const float* W    = (const float*)d_in[3];
    float*       out  = (float*)d_out;

    float* wm = (float*)d_ws;                // 640 floats (2.5 KB)
    float* v1 = (float*)d_ws + 1024;         // +4 KB: intermediate v (512 KB)

    softmax_w_kernel<<<1, 64, 0, stream>>>(W, wm);

    dim3 grid(G_TOT / GPB, B_TOT / B_PER);   // (64, 8) = 512 blocks
    step_kernel<<<grid, THREADS, 0, stream>>>(v0, X, fact, wm, v1);
    step_kernel<<<grid, THREADS, 0, stream>>>(v1, X, fact, wm, out);
}

// Round 2
// 43.976 us; speedup vs baseline: 1.1160x; 1.1160x over previous
//
#include <hip/hip_runtime.h>
#include <math.h>

// Problem constants (from reference setup_inputs)
#define B_TOT 32
#define C_TOT 128
#define G_TOT 4096
#define BODY  4
#define M_TOT 5

// Tiling
#define B_PER 4            // batch rows per block, packed as float4 per g in LDS
#define CQ    8            // c-loop split across 8 adjacent lanes
#define GPB   64           // g outputs per block
#define THREADS (GPB*CQ)   // 512
#define C_PER (C_TOT/CQ)   // 16 c-iterations per thread

typedef float f32x2 __attribute__((ext_vector_type(2)));

__device__ __forceinline__ f32x2 pk_mul(f32x2 a, f32x2 b) {
    f32x2 d;
    asm("v_pk_mul_f32 %0, %1, %2" : "=v"(d) : "v"(a), "v"(b));
    return d;
}
__device__ __forceinline__ void pk_fma(f32x2& d, f32x2 a, f32x2 b) {
    asm("v_pk_fma_f32 %0, %1, %2, %0" : "+v"(d) : "v"(a), "v"(b));
}

// ---- softmax over W rows (5 x 128), transposed+padded output wt[c][8] ----
__global__ void softmax_w_kernel(const float* __restrict__ W, float* __restrict__ Wt) {
    const int lane = threadIdx.x; // 64 threads
    for (int m = 0; m < M_TOT; ++m) {
        float a = W[m * C_TOT + lane];
        float b = W[m * C_TOT + lane + 64];
        float mx = fmaxf(a, b);
        #pragma unroll
        for (int off = 32; off; off >>= 1) mx = fmaxf(mx, __shfl_xor(mx, off));
        float ea = expf(a - mx), eb = expf(b - mx);
        float s = ea + eb;
        #pragma unroll
        for (int off = 32; off; off >>= 1) s += __shfl_xor(s, off);
        Wt[lane * 8 + m]        = ea / s;
        Wt[(lane + 64) * 8 + m] = eb / s;
    }
}

// ---- one t-step: v_out = softor(v_in, softor_m(h)) ----
__global__ __launch_bounds__(THREADS, 4) void step_kernel(
    const float* __restrict__ v_in,   // (B, G)
    const int*   __restrict__ X,      // (C, G, 4) int32
    const int*   __restrict__ fact,   // (C, G) int32 (0/1)
    const float* __restrict__ Wt,     // (128, 8) softmaxed, transposed, padded
    float*       __restrict__ v_out)  // (B, G)
{
    __shared__ float4 lv4[G_TOT];      // 64 KB: v[b0..b0+3][g] packed per g
    __shared__ float  lwt[C_TOT * 8];  // 4 KB

    const int tid = threadIdx.x;
    const int b0  = blockIdx.y * B_PER;
    const int gt  = blockIdx.x * GPB;

    // stage Wt
    for (int i = tid; i < C_TOT * 8; i += THREADS) lwt[i] = Wt[i];

    // stage v transposed: coalesced global reads per row, conflict-free b128 writes
    for (int g = tid; g < G_TOT; g += THREADS) {
        float4 t;
        t.x = v_in[(size_t)(b0 + 0) * G_TOT + g];
        t.y = v_in[(size_t)(b0 + 1) * G_TOT + g];
        t.z = v_in[(size_t)(b0 + 2) * G_TOT + g];
        t.w = v_in[(size_t)(b0 + 3) * G_TOT + g];
        lv4[g] = t;
    }
    __syncthreads();

    const int cq = tid & (CQ - 1);
    const int gl = tid >> 3;
    const int g  = gt + gl;

    f32x2 hlo[M_TOT], hhi[M_TOT];
    #pragma unroll
    for (int m = 0; m < M_TOT; ++m) { hlo[m] = (f32x2){0.f, 0.f}; hhi[m] = (f32x2){0.f, 0.f}; }

    const f32x2 one2 = (f32x2){1.f, 1.f};

    #pragma unroll 4
    for (int ci = 0; ci < C_PER; ++ci) {
        const int c = ci * CQ + cq;                 // interleaved c-partition
        const int4 xi = ((const int4*)X)[(size_t)c * G_TOT + g];
        const int  fm = fact[(size_t)c * G_TOT + g];
        const float* wp = &lwt[c * 8];

        const float4 va = lv4[xi.x];
        const float4 vb = lv4[xi.y];
        const float4 vc = lv4[xi.z];
        const float4 vd = lv4[xi.w];

        f32x2 plo = pk_mul(pk_mul((f32x2){va.x, va.y}, (f32x2){vb.x, vb.y}),
                           pk_mul((f32x2){vc.x, vc.y}, (f32x2){vd.x, vd.y}));
        f32x2 phi = pk_mul(pk_mul((f32x2){va.z, va.w}, (f32x2){vb.z, vb.w}),
                           pk_mul((f32x2){vc.z, vc.w}, (f32x2){vd.z, vd.w}));
        plo = fm ? one2 : plo;
        phi = fm ? one2 : phi;

        #pragma unroll
        for (int m = 0; m < M_TOT; ++m) {
            const float w = wp[m];
            const f32x2 ws = (f32x2){w, w};
            pk_fma(hlo[m], plo, ws);
            pk_fma(hhi[m], phi, ws);
        }
    }

    // butterfly reduce over the 8 cq lanes; all lanes end with full sums
    float hs[M_TOT][B_PER];
    #pragma unroll
    for (int m = 0; m < M_TOT; ++m) {
        hs[m][0] = hlo[m].x; hs[m][1] = hlo[m].y;
        hs[m][2] = hhi[m].x; hs[m][3] = hhi[m].y;
    }
    #pragma unroll
    for (int m = 0; m < M_TOT; ++m)
        #pragma unroll
        for (int b = 0; b < B_PER; ++b) {
            float s = hs[m][b];
            s += __shfl_xor(s, 1);
            s += __shfl_xor(s, 2);
            s += __shfl_xor(s, 4);
            hs[m][b] = s;
        }

    // epilogue: 4 of the 8 cq lanes each write one b
    if (cq < B_PER) {
        const int b = cq;
        float om = 1.0f;
        #pragma unroll
        for (int m = 0; m < M_TOT; ++m) om *= (1.0f - hs[m][b]);
        float r = 1.0f - om;
        r = fminf(fmaxf(r, 0.0f), 1.0f);
        const float vold = ((const float*)lv4)[g * 4 + b];
        float vn = 1.0f - (1.0f - vold) * (1.0f - r);
        vn = fminf(fmaxf(vn, 0.0f), 1.0f);
        v_out[(size_t)(b0 + b) * G_TOT + g] = vn;
    }
}

extern "C" void kernel_launch(void* const* d_in, const int* in_sizes, int n_in,
                              void* d_out, int out_size, void* d_ws, size_t ws_size,
                              hipStream_t stream) {
    const float* v0   = (const float*)d_in[0];
    const int*   X    = (const int*)  d_in[1];   // int64 in ref -> int32 on device
    const int*   fact = (const int*)  d_in[2];   // bool in ref  -> int32 on device
    const float* W    = (const float*)d_in[3];
    float*       out  = (float*)d_out;

    float* wt = (float*)d_ws;                // 1024 floats (4 KB), wt[c][8]
    float* v1 = (float*)d_ws + 1024;         // intermediate v (512 KB)

    softmax_w_kernel<<<1, 64, 0, stream>>>(W, wt);

    dim3 grid(G_TOT / GPB, B_TOT / B_PER);   // (64, 8) = 512 blocks
    step_kernel<<<grid, THREADS, 0, stream>>>(v0, X, fact, wt, v1);
    step_kernel<<<grid, THREADS, 0, stream>>>(v1, X, fact, wt, out);
}